// Round 8
// baseline (89.757 us; speedup 1.0000x reference)
//
#include <hip/hip_runtime.h>

// Depth-4 path signature, C=10, L=64, B=2048 — MFMA formulation (R7).
// Closed form: with exclusive prefix P_t = sum_{s<t} dx_s, suffix R_r =
// P_63 - P_{r+1}, and per-step level-2 scalars
//   u1=P+di/4, v1=P+di/3, w1=P+di/2, u2=s2+u1*dj/3, v2=s2+v1*dj/2,
//   s2+=w1*dj   (s2 runs the exclusive level-2 prefix; final s2 = S2)
// then  S3[ij,k]  = sum_t v2_t[ij]*dx_t[k]
//       S4[ij,kl] = sum_r v2_r[ij]*(dx_r[k]*R_r[l]) + sum_t u2_t[ij]*(dx_t[k]*dx_t[l]/2)
// => one bf16 GEMM per batch elem: A(100x128) = [V2(k=t) | U2(k=64+t)],
//    B(128x110): rows k<64: [dx_k ox R_k | dx_k], rows k>=64: [dx ox dx /2 | 0],
//    C(100x110): cols 0..99 = S4, cols 100..109 = S3. K slots 63,127 zero.
// A/B stored with identical per-(row|col) XOR-swizzled k addressing, so the
// MFMA k-slot mapping cancels (contraction symmetric in k-slots). C/D layout
// (verified): col = lane&15, row = (lane>>4)*4 + reg.

typedef short short8 __attribute__((ext_vector_type(8)));
typedef float f32x4 __attribute__((ext_vector_type(4)));

constexpr int C = 10, L = 64, T = 63;          // T = L-1 steps
constexpr int OUTSZ = 10 + 100 + 1000 + 10000; // 11110
constexpr int DXP = 13;                        // dx/P row stride (fp32 words)
constexpr int KS = 136;                        // A/B k-stride in shorts (272B)

__device__ __forceinline__ unsigned short f2bf(float f) {  // RNE f32->bf16
  unsigned u = __float_as_uint(f);
  return (unsigned short)((u + 0x7FFFu + ((u >> 16) & 1u)) >> 16);
}
__device__ __forceinline__ int swz(int row, int k) {  // short-index w/ XOR swizzle
  return row * KS + (k ^ ((row & 7) << 3));
}

__global__ __launch_bounds__(256, 2) void sig4_kernel(
    const float* __restrict__ x, float* __restrict__ out)
{
  __shared__ __align__(16) unsigned short Ab[100 * KS];  // 27.2 KB
  __shared__ __align__(16) unsigned short Bb[110 * KS];  // 29.9 KB
  __shared__ float dxs[T * DXP];
  __shared__ float Ps[64 * DXP];

  const int t = threadIdx.x;
  const float* __restrict__ xb = x + (size_t)blockIdx.x * (C * L);
  float* __restrict__ ob = out + (size_t)blockIdx.x * OUTSZ;

  // ---- phase A: path -> dx, exclusive prefix P (shuffle scan) ----
  float* pl = (float*)Bb;  // alias: Bb written only after last pl read
  for (int i = t; i < C * L; i += 256) pl[i] = xb[i];
  __syncthreads();
  for (int i = t; i < T * C; i += 256) {
    int s = i / C, c = i - s * C;
    dxs[s * DXP + c] = pl[c * L + s + 1] - pl[c * L + s];
  }
  __syncthreads();
  {
    int w = t >> 6, lane = t & 63;
    for (int c = w; c < C; c += 4) {
      float v = (lane > 0) ? dxs[(lane - 1) * DXP + c] : 0.f;
      #pragma unroll
      for (int d = 1; d < 64; d <<= 1) {
        float y = __shfl_up(v, d);
        if (lane >= d) v += y;
      }
      Ps[lane * DXP + c] = v;   // P[t][c] = sum_{s<t} dx_s[c]; P[63] = S1
    }
  }
  __syncthreads();

  // ---- phase B: sequential A-build (waves 0-1) || B-build (waves 2-3) ----
  if (t < 128) {
    if (t < 100) {
      const int i_ = t / 10, j_ = t - i_ * 10;
      float s2 = 0.f;
      for (int s = 0; s < T; ++s) {
        float di = dxs[s * DXP + i_];
        float dj = dxs[s * DXP + j_];
        float p  = Ps[s * DXP + i_];
        float u2 = fmaf(fmaf(di, 0.25f, p), dj * (1.f / 3.f), s2);
        float v2 = fmaf(fmaf(di, (1.f / 3.f), p), dj * 0.5f, s2);
        s2 = fmaf(fmaf(di, 0.5f, p), dj, s2);
        Ab[swz(t, s)]      = f2bf(v2);
        Ab[swz(t, 64 + s)] = f2bf(u2);
      }
      Ab[swz(t, 63)]  = 0;
      Ab[swz(t, 127)] = 0;
      ob[10 + t] = s2;                            // S2 (exact fp32)
      if (j_ == 0) ob[i_] = Ps[63 * DXP + i_];    // S1
    }
  } else {
    const int q = t - 128;
    for (int idx = q; idx < 110 * 64; idx += 128) {  // 55 iters
      int col = idx >> 6, kk = idx & 63;
      float b1 = 0.f, b2 = 0.f;
      if (col < 100 && kk < 63) {
        int k2 = col / 10, l2 = col - k2 * 10;
        float d  = dxs[kk * DXP + k2];
        float dl = dxs[kk * DXP + l2];
        float R  = Ps[63 * DXP + l2] - Ps[(kk + 1) * DXP + l2];
        b1 = d * R;
        b2 = d * dl * 0.5f;
      } else if (col >= 100 && kk < 63) {
        b1 = dxs[kk * DXP + (col - 100)];
      }
      Bb[swz(col, kk)]      = f2bf(b1);
      Bb[swz(col, 64 + kk)] = f2bf(b2);
    }
  }
  __syncthreads();

  // ---- phase C: per-block GEMM C(100x110) = A(100x128) x B(128x110) ----
  const int w = t >> 6, lane = t & 63;
  const int lm = lane & 15, lg = lane >> 4;
  for (int rt = w; rt < 7; rt += 4) {            // waves: {0,4},{1,5},{2,6},{3}
    const int arow = rt * 16 + lm;
    short8 a[4];
    #pragma unroll
    for (int ks = 0; ks < 4; ++ks)
      a[ks] = (arow < 100) ? *(const short8*)&Ab[swz(arow, ks * 32 + lg * 8)]
                           : short8{0, 0, 0, 0, 0, 0, 0, 0};
    for (int ct = 0; ct < 7; ++ct) {
      const int bcol = ct * 16 + lm;
      f32x4 acc = {0.f, 0.f, 0.f, 0.f};
      #pragma unroll
      for (int ks = 0; ks < 4; ++ks) {
        short8 bf = (bcol < 110)
            ? *(const short8*)&Bb[swz(bcol, ks * 32 + lg * 8)]
            : short8{0, 0, 0, 0, 0, 0, 0, 0};
        acc = __builtin_amdgcn_mfma_f32_16x16x32_bf16(a[ks], bf, acc, 0, 0, 0);
      }
      const int rbase = rt * 16 + lg * 4;
      #pragma unroll
      for (int r = 0; r < 4; ++r) {
        int row = rbase + r;
        if (row < 100) {
          if (bcol < 100)      ob[1110 + row * 100 + bcol] = acc[r];
          else if (bcol < 110) ob[110 + row * 10 + (bcol - 100)] = acc[r];
        }
      }
    }
  }
}

extern "C" void kernel_launch(void* const* d_in, const int* in_sizes, int n_in,
                              void* d_out, int out_size, void* d_ws, size_t ws_size,
                              hipStream_t stream) {
  const float* x = (const float*)d_in[0];
  float* out = (float*)d_out;
  const int batch = in_sizes[0] / (C * L);   // 2048
  sig4_kernel<<<dim3(batch), dim3(256), 0, stream>>>(x, out);
}

// Round 9
// 49.942 us; speedup vs baseline: 1.7972x; 1.7972x over previous
//
#include <hip/hip_runtime.h>

// Depth-4 path signature, C=10, L=64, B=2048 — MFMA formulation (R9).
// Same closed form as R7/R8 (validated, absmax 5.25):
//   P_t = exclusive prefix of dx;  R_t[l] = S1[l] - P_{t+1}[l]
//   per (i,j): s2 sequential; u2_t, v2_t -> A(100x128) = [V2 | U2]
//   B(128x110): k<64: [dx_k ox R_k | dx_k], k>=64: [dx ox dx /2 | 0]
//   C(100x110) = A x B: cols 0..99 = S4, 100..109 = S3.
// R9 vs R8: LDS layout fix. R8's per-short XOR swizzle made phase-B writes
// (fixed k, varying row; row stride == 4 words mod 32) a ~16-way conflict ->
// 18.7M conflict cycles. Now: (a) 16B-granule swizzle
//   off = row*136 + ((k>>3 ^ (row&7))<<3) + (k&7)
// (b) phase-B buffers 8 k-values in registers and writes ds_write_b128 along
// k (A-build: 2 writes per 8 steps; B-build: 8-wide k-chunk tasks).

typedef short short8 __attribute__((ext_vector_type(8)));
typedef float f32x4 __attribute__((ext_vector_type(4)));
typedef unsigned int uint4v __attribute__((ext_vector_type(4)));

constexpr int C = 10, L = 64, T = 63;          // T = L-1 steps
constexpr int OUTSZ = 10 + 100 + 1000 + 10000; // 11110
constexpr int DXP = 13;                        // dx/P row stride (fp32 words)
constexpr int KS = 136;                        // A/B row stride in shorts (272B, 16B-mult)

__device__ __forceinline__ unsigned short f2bf(float f) {  // RNE f32->bf16
  unsigned u = __float_as_uint(f);
  return (unsigned short)((u + 0x7FFFu + ((u >> 16) & 1u)) >> 16);
}
__device__ __forceinline__ int swz(int row, int k) {  // short index, 16B-granule XOR
  return row * KS + ((((k >> 3) ^ (row & 7)) << 3) | (k & 7));
}

__global__ __launch_bounds__(256, 2) void sig4_kernel(
    const float* __restrict__ x, float* __restrict__ out)
{
  __shared__ __align__(16) unsigned short Ab[100 * KS];  // 27.2 KB
  __shared__ __align__(16) unsigned short Bb[110 * KS];  // 29.9 KB
  __shared__ float dxs[T * DXP];
  __shared__ float Ps[64 * DXP];

  const int t = threadIdx.x;
  const float* __restrict__ xb = x + (size_t)blockIdx.x * (C * L);
  float* __restrict__ ob = out + (size_t)blockIdx.x * OUTSZ;

  // ---- phase A: path -> dx, exclusive prefix P (shuffle scan) ----
  float* pl = (float*)Bb;  // alias: Bb written only after last pl read
  for (int i = t; i < C * L; i += 256) pl[i] = xb[i];
  __syncthreads();
  for (int i = t; i < T * C; i += 256) {
    int s = i / C, c = i - s * C;
    dxs[s * DXP + c] = pl[c * L + s + 1] - pl[c * L + s];
  }
  __syncthreads();
  {
    int w = t >> 6, lane = t & 63;
    for (int c = w; c < C; c += 4) {
      float v = (lane > 0) ? dxs[(lane - 1) * DXP + c] : 0.f;
      #pragma unroll
      for (int d = 1; d < 64; d <<= 1) {
        float y = __shfl_up(v, d);
        if (lane >= d) v += y;
      }
      Ps[lane * DXP + c] = v;   // P[t][c] = sum_{s<t} dx_s[c]; P[63] = S1
    }
  }
  __syncthreads();

  // ---- phase B: A-build (lanes 0..99) || B-build (lanes 128..255) ----
  if (t < 100) {
    const int i_ = t / 10, j_ = t - i_ * 10;
    float s2 = 0.f;
    #pragma unroll
    for (int ch = 0; ch < 8; ++ch) {     // 8 steps per chunk -> 2 b128 writes
      unsigned vpk[4], upk[4];
      #pragma unroll
      for (int e = 0; e < 8; ++e) {
        const int s = ch * 8 + e;
        float u2 = 0.f, v2 = 0.f;
        if (s < T) {
          float di = dxs[s * DXP + i_];
          float dj = dxs[s * DXP + j_];
          float p  = Ps[s * DXP + i_];
          u2 = fmaf(fmaf(di, 0.25f, p), dj * (1.f / 3.f), s2);
          v2 = fmaf(fmaf(di, (1.f / 3.f), p), dj * 0.5f, s2);
          s2 = fmaf(fmaf(di, 0.5f, p), dj, s2);
        }
        unsigned vb = f2bf(v2), ub = f2bf(u2);
        if ((e & 1) == 0) { vpk[e >> 1] = vb; upk[e >> 1] = ub; }
        else             { vpk[e >> 1] |= vb << 16; upk[e >> 1] |= ub << 16; }
      }
      *(uint4v*)&Ab[swz(t, ch * 8)]      = uint4v{vpk[0], vpk[1], vpk[2], vpk[3]};
      *(uint4v*)&Ab[swz(t, 64 + ch * 8)] = uint4v{upk[0], upk[1], upk[2], upk[3]};
    }
    ob[10 + t] = s2;                            // S2 (exact fp32)
    if (j_ == 0) ob[i_] = Ps[63 * DXP + i_];    // S1
  } else if (t >= 128) {
    const int q = t - 128;
    for (int task = q; task < 110 * 8; task += 128) {  // (col, k-chunk) tasks
      const int col = task >> 3, ch = task & 7;
      unsigned b1pk[4], b2pk[4];
      if (col < 100) {
        const int k2 = col / 10, l2 = col - k2 * 10;
        const float S1l = Ps[63 * DXP + l2];
        #pragma unroll
        for (int e = 0; e < 8; ++e) {
          const int kk = ch * 8 + e;
          float b1 = 0.f, b2 = 0.f;
          if (kk < T) {
            float d  = dxs[kk * DXP + k2];
            float dl = dxs[kk * DXP + l2];
            float R  = S1l - Ps[(kk + 1) * DXP + l2];
            b1 = d * R;
            b2 = d * dl * 0.5f;
          }
          unsigned x1 = f2bf(b1), x2 = f2bf(b2);
          if ((e & 1) == 0) { b1pk[e >> 1] = x1; b2pk[e >> 1] = x2; }
          else             { b1pk[e >> 1] |= x1 << 16; b2pk[e >> 1] |= x2 << 16; }
        }
      } else {
        const int c2 = col - 100;
        #pragma unroll
        for (int e = 0; e < 8; ++e) {
          const int kk = ch * 8 + e;
          float b1 = (kk < T) ? dxs[kk * DXP + c2] : 0.f;
          unsigned x1 = f2bf(b1);
          if ((e & 1) == 0) { b1pk[e >> 1] = x1; b2pk[e >> 1] = 0u; }
          else             { b1pk[e >> 1] |= x1 << 16; }
        }
      }
      *(uint4v*)&Bb[swz(col, ch * 8)]      = uint4v{b1pk[0], b1pk[1], b1pk[2], b1pk[3]};
      *(uint4v*)&Bb[swz(col, 64 + ch * 8)] = uint4v{b2pk[0], b2pk[1], b2pk[2], b2pk[3]};
    }
  }
  __syncthreads();

  // ---- phase C: per-block GEMM C(100x110) = A(100x128) x B(128x110) ----
  const int w = t >> 6, lane = t & 63;
  const int lm = lane & 15, lg = lane >> 4;
  for (int rt = w; rt < 7; rt += 4) {            // waves: {0,4},{1,5},{2,6},{3}
    const int arow = rt * 16 + lm;
    short8 a[4];
    #pragma unroll
    for (int ks = 0; ks < 4; ++ks)
      a[ks] = (arow < 100) ? *(const short8*)&Ab[swz(arow, ks * 32 + lg * 8)]
                           : short8{0, 0, 0, 0, 0, 0, 0, 0};
    for (int ct = 0; ct < 7; ++ct) {
      const int bcol = ct * 16 + lm;
      f32x4 acc = {0.f, 0.f, 0.f, 0.f};
      #pragma unroll
      for (int ks = 0; ks < 4; ++ks) {
        short8 bf = (bcol < 110)
            ? *(const short8*)&Bb[swz(bcol, ks * 32 + lg * 8)]
            : short8{0, 0, 0, 0, 0, 0, 0, 0};
        acc = __builtin_amdgcn_mfma_f32_16x16x32_bf16(a[ks], bf, acc, 0, 0, 0);
      }
      const int rbase = rt * 16 + lg * 4;
      #pragma unroll
      for (int r = 0; r < 4; ++r) {
        int row = rbase + r;
        if (row < 100) {
          if (bcol < 100)      ob[1110 + row * 100 + bcol] = acc[r];
          else if (bcol < 110) ob[110 + row * 10 + (bcol - 100)] = acc[r];
        }
      }
    }
  }
}

extern "C" void kernel_launch(void* const* d_in, const int* in_sizes, int n_in,
                              void* d_out, int out_size, void* d_ws, size_t ws_size,
                              hipStream_t stream) {
  const float* x = (const float*)d_in[0];
  float* out = (float*)d_out;
  const int batch = in_sizes[0] / (C * L);   // 2048
  sig4_kernel<<<dim3(batch), dim3(256), 0, stream>>>(x, out);
}